// Round 5
// baseline (214.984 us; speedup 1.0000x reference)
//
#include <hip/hip_runtime.h>

// CausalSelfAttention on MI355X (gfx950), bf16 MFMA pipeline.
// B=2 T=2048 C=1024 NH=16 HD=64.  M=B*T=4096.
//
// R16: operand-swapped GEMM epilogues.  R4 counters: QKV WRITE_SIZE 40.9 MB
// vs 24 MB logical (1.7x partial-line write amplification) + VALUBusy 30% >
// MfmaUtil 20% — the q/k epilogue's 64 scalar 2-B stores/thread are the
// culprit.  Swapping MFMA operands (MFMA(b,a) instead of MFMA(a,b))
// transposes the C fragment: each thread then holds 4 consecutive n (=d)
// at fixed m -> one aligned 8-B short4v store per fragment (16 stores vs 64).
// v-section keeps original order (V^T wants m-consecutive, already packed).
// proj GEMM swapped too: epilogue = 16 float4 stores (full-line coalesced).
// Same dot products, same accumulation order per element — numerically exact.

typedef __attribute__((ext_vector_type(8))) short short8;   // 8 x bf16 (4 VGPR)
typedef __attribute__((ext_vector_type(4))) short short4v;  // 4 x bf16 (2 VGPR, align 8)
typedef __attribute__((ext_vector_type(4))) float f32x4;    // MFMA 16x16 acc
typedef __attribute__((ext_vector_type(2))) unsigned int u32x2;

#define MFMA16(a, b, c) __builtin_amdgcn_mfma_f32_16x16x32_bf16((a), (b), (c), 0, 0, 0)
#define MFMA16K16(a, b, c) __builtin_amdgcn_mfma_f32_16x16x16bf16_1k((a), (b), (c), 0, 0, 0)

__device__ __forceinline__ unsigned short f2bf(float f) {
  unsigned u = __builtin_bit_cast(unsigned, f);
  u += 0x7fffu + ((u >> 16) & 1u);   // RNE
  return (unsigned short)(u >> 16);
}

__device__ __forceinline__ unsigned short f2bf_fast(float f) {
  // round-half-up: cheaper (2 VALU); |err| <= 2^-9 rel, fine for P/y
  return (unsigned short)((__builtin_bit_cast(unsigned, f) + 0x8000u) >> 16);
}

#if __has_builtin(__builtin_amdgcn_cvt_pk_bf16_f32)
typedef __attribute__((ext_vector_type(2))) __bf16 bf16x2;
__device__ __forceinline__ short4v pack_bf16x4(float a, float b, float c, float d) {
  bf16x2 lo = __builtin_amdgcn_cvt_pk_bf16_f32(a, b);
  bf16x2 hi = __builtin_amdgcn_cvt_pk_bf16_f32(c, d);
  u32x2 t;
  t[0] = __builtin_bit_cast(unsigned, lo);
  t[1] = __builtin_bit_cast(unsigned, hi);
  return __builtin_bit_cast(short4v, t);
}
#else
__device__ __forceinline__ short4v pack_bf16x4(float a, float b, float c, float d) {
  short4v r;
  r[0] = (short)f2bf_fast(a); r[1] = (short)f2bf_fast(b);
  r[2] = (short)f2bf_fast(c); r[3] = (short)f2bf_fast(d);
  return r;
}
#endif

__device__ __forceinline__ short4v pack_rne4(float a, float b, float c, float d) {
  short4v r;
  r[0] = (short)f2bf(a); r[1] = (short)f2bf(b);
  r[2] = (short)f2bf(c); r[3] = (short)f2bf(d);
  return r;
}

__device__ __forceinline__ void gl2lds16(const void* g, void* l) {
  // async global->LDS, 16B/lane; LDS dest = wave-uniform base + lane*16
  __builtin_amdgcn_global_load_lds(
      (__attribute__((address_space(1))) void*)g,
      (__attribute__((address_space(3))) void*)l,
      16, 0, 0);
}

// ---------------- merged prep: x->bf16 + both weight transposes ----------------
// blocks [0,4096): conv x (4096x1024 fp32 -> bf16)
// blocks [4096,4864): Wqkv (1024x3072) -> Wqkv^T bf16 (3072x1024), 48x16 tiles
// blocks [4864,5120): Wproj (1024x1024) -> Wproj^T bf16, 16x16 tiles
// Branch is block-uniform, so the __syncthreads in the transpose path is safe.
__global__ __launch_bounds__(256)
void prep(const float* __restrict__ x, unsigned short* __restrict__ xb,
          const float* __restrict__ Wqkv, unsigned short* __restrict__ wqkvT,
          const float* __restrict__ Wproj, unsigned short* __restrict__ wprojT) {
  __shared__ float tile[64][65];
  const int bx = blockIdx.x, tid = threadIdx.x;
  if (bx < 4096) {
    const int i = (bx * 256 + tid) * 4;
    float4 f = *(const float4*)(x + i);
    unsigned long long r = (unsigned long long)f2bf(f.x)
        | ((unsigned long long)f2bf(f.y) << 16)
        | ((unsigned long long)f2bf(f.z) << 32)
        | ((unsigned long long)f2bf(f.w) << 48);
    *(unsigned long long*)(xb + i) = r;
    return;
  }
  const float* W;
  unsigned short* WT;
  int n0, k0, N;
  if (bx < 4864) {
    const int idx = bx - 4096;            // 48 x 16 tiles, N=3072
    W = Wqkv; WT = wqkvT; N = 3072;
    n0 = (idx % 48) * 64; k0 = (idx / 48) * 64;
  } else {
    const int idx = bx - 4864;            // 16 x 16 tiles, N=1024
    W = Wproj; WT = wprojT; N = 1024;
    n0 = (idx % 16) * 64; k0 = (idx / 16) * 64;
  }
  const int K = 1024;
  const int c = tid & 63, rbase = tid >> 6;  // 4 rows per pass, 16 passes
#pragma unroll
  for (int i = 0; i < 16; ++i) {
    int r = i * 4 + rbase;
    tile[r][c] = W[(size_t)(k0 + r) * N + n0 + c];
  }
  __syncthreads();
#pragma unroll
  for (int i = 0; i < 16; ++i) {
    int r = i * 4 + rbase;
    WT[(size_t)(n0 + r) * K + k0 + c] = f2bf(tile[c][r]);
  }
}

// ---------------- GEMM: C = A(MxK) * BT(NxK)^T ----------------
// BK=64, XOR-swizzled LDS staging (conflict-free ds_read_b128 fragments).
// MT = M-tile (128 or 64); N-tile fixed 128.  R1 structure (proven best):
// single-buffered 32 KB LDS -> ~3 blocks/CU; stage -> sync -> compute -> sync.
// Operand order per section (R16):
//   swapped  (MFMA(b,a)): thread holds 4 consecutive n at fixed m
//     -> q/k epilogue: short4v (8 B) stores into (B,H,T,D)
//     -> proj epilogue: float4 stores into row-major fp32
//   original (MFMA(a,b)): thread holds 4 consecutive m at fixed n
//     -> v epilogue: short4v stores into V^T (B,H,D,T)
// EPI==0: QKV epilogue -> q (B,H,T,D) PRE-SCALED by 0.125*log2(e),
//         k (B,H,T,D), v (B,H,D,T) bf16
// EPI==1: proj epilogue -> fp32 out + bias
template <int EPI, int MT>
__global__ __launch_bounds__(256)
void gemm_bt(const unsigned short* __restrict__ A,
             const unsigned short* __restrict__ BT,
             const float* __restrict__ bias,
             float* __restrict__ outF,
             unsigned short* __restrict__ q_out,
             unsigned short* __restrict__ k_out,
             unsigned short* __restrict__ vT_out,
             int Ndim, int Kdim) {
  constexpr int IF = MT / 32;                 // A-frags per wave per ksub
  constexpr int RA = MT / 32;                 // A staging rounds (32 rows each)
  __shared__ __align__(16) unsigned short As[MT * 64];
  __shared__ __align__(16) unsigned short Bs[128 * 64];
  const int tid = threadIdx.x;
  const int wave = tid >> 6, lane = tid & 63;
  const int quad = lane >> 4, lr = lane & 15;
  const int wm = wave >> 1, wn = wave & 1;
  const int m0 = blockIdx.y * MT, n0 = blockIdx.x * 128;

  // v-section (EPI==0, n0>=2048) keeps original operand order; all else swapped
  const bool vsec = (EPI == 0) && (n0 >= 2048);

  const int r_l = tid >> 3;
  const int cg = (tid & 7) ^ (r_l & 7);
  const unsigned short* gA = A + (size_t)(m0 + r_l) * Kdim + cg * 8;
  const unsigned short* gB = BT + (size_t)(n0 + r_l) * Kdim + cg * 8;
  const size_t rstep = (size_t)32 * Kdim;

  f32x4 acc[IF][4] = {};
  for (int k0 = 0; k0 < Kdim; k0 += 64) {
#pragma unroll
    for (int rd = 0; rd < RA; ++rd)
      gl2lds16(gA + k0 + rd * rstep, As + rd * 2048 + wave * 512);
#pragma unroll
    for (int rd = 0; rd < 4; ++rd)
      gl2lds16(gB + k0 + rd * rstep, Bs + rd * 2048 + wave * 512);
    __syncthreads();
#pragma unroll
    for (int s = 0; s < 2; ++s) {
      const int sw = ((s * 4 + quad) ^ (lr & 7)) * 8;
      short8 a[IF], b[4];
#pragma unroll
      for (int i = 0; i < IF; ++i)
        a[i] = *(const short8*)(As + (wm * (MT / 2) + i * 16 + lr) * 64 + sw);
#pragma unroll
      for (int j = 0; j < 4; ++j)
        b[j] = *(const short8*)(Bs + (wn * 64 + j * 16 + lr) * 64 + sw);
      if (vsec) {
#pragma unroll
        for (int i = 0; i < IF; ++i)
#pragma unroll
          for (int j = 0; j < 4; ++j)
            acc[i][j] = MFMA16(a[i], b[j], acc[i][j]);
      } else {
#pragma unroll
        for (int i = 0; i < IF; ++i)
#pragma unroll
          for (int j = 0; j < 4; ++j)
            acc[i][j] = MFMA16(b[j], a[i], acc[i][j]);
      }
    }
    __syncthreads();
  }

  if (EPI == 0) {
    const int sec = n0 >> 10;                 // block-uniform
    if (sec == 2) {
      // v (original order): C[m][n], thread: m = m0+wm*64+quad*4+i*16+{r},
      // n = n0+wn*64+lr+j*16.  Pack 4 m-consecutive (=t) -> V^T (B,H,D,T).
      const int row_t = wm * (MT / 2) + quad * 4;
      const int col_t = wn * 64 + lr;
#pragma unroll
      for (int j = 0; j < 4; ++j) {
        const int n = n0 + col_t + j * 16;
        const float bi = bias[n];
        const int nn = n & 1023, h = nn >> 6, d = nn & 63;
#pragma unroll
        for (int i = 0; i < IF; ++i) {
          const int m_base = m0 + row_t + i * 16;   // 4 consecutive m
          const int bb = m_base >> 11, t0 = m_base & 2047;
          const int bh = bb * 16 + h;
          short4v pk = pack_rne4(acc[i][j][0] + bi, acc[i][j][1] + bi,
                                 acc[i][j][2] + bi, acc[i][j][3] + bi);
          *(short4v*)(vT_out + ((size_t)bh * 64 + d) * 2048 + t0) = pk;
        }
      }
    } else {
      // q/k (swapped): C[m][n], thread: m = m0+wm*64+i*16+lr,
      // n = n0+wn*64+j*16+quad*4+{r}.  Pack 4 n-consecutive (=d) -> (B,H,T,D).
      const float scl = (sec == 0) ? 0.18033688f : 1.0f;  // 0.125*log2(e) into Q
      unsigned short* outb = (sec == 0) ? q_out : k_out;
      const int bb = m0 >> 11;                            // block-uniform
      const int hh = ((n0 & 1023) >> 6) + wn;             // wave-uniform head
      unsigned short* dst0 = outb + (size_t)(bb * 16 + hh) * 131072;
#pragma unroll
      for (int j = 0; j < 4; ++j) {
        const int nb = wn * 64 + j * 16 + quad * 4;       // n_loc base
        const float4 bi = *(const float4*)(bias + n0 + nb);
        const int d0 = j * 16 + quad * 4;                 // (nb & 63)
#pragma unroll
        for (int i = 0; i < IF; ++i) {
          const int t0 = (m0 & 2047) + wm * (MT / 2) + i * 16 + lr;
          short4v pk = pack_rne4((acc[i][j][0] + bi.x) * scl,
                                 (acc[i][j][1] + bi.y) * scl,
                                 (acc[i][j][2] + bi.z) * scl,
                                 (acc[i][j][3] + bi.w) * scl);
          *(short4v*)(dst0 + (size_t)t0 * 64 + d0) = pk;
        }
      }
    }
  } else {
    // proj (swapped): float4 store, full-line coalesced across quads
#pragma unroll
    for (int j = 0; j < 4; ++j) {
      const int nb = n0 + wn * 64 + j * 16 + quad * 4;
      const float4 bi = *(const float4*)(bias + nb);
#pragma unroll
      for (int i = 0; i < IF; ++i) {
        const int m = m0 + wm * (MT / 2) + i * 16 + lr;
        float4 o4;
        o4.x = acc[i][j][0] + bi.x;
        o4.y = acc[i][j][1] + bi.y;
        o4.z = acc[i][j][2] + bi.z;
        o4.w = acc[i][j][3] + bi.w;
        *(float4*)(outF + (size_t)m * Ndim + nb) = o4;
      }
    }
  }
}

// ---------------- flash-style causal attention, 64-row q-tiles ----------------
// m=0 softmax; Q PRE-SCALED by 0.125*log2(e) so P = exp2(S).
// Transposed-S trick: S^T = K*Q^T; its C-layout IS the K=16 A-operand layout.
// Block = 4 waves x 16 q-rows = 64 q-rows; K/V fragment LDS reads shared.
// 1024 blocks, heavy-first (LPT) dispatch, bh%8 pins XCD for K/V L2 locality.
// Triple-buffered K/V staged TWO tiles ahead; raw s_barrier + manual
// s_waitcnt vmcnt(4) so the newest stage stays in flight across the barrier.
// T5 s_setprio(1) around MFMA clusters (independent blocks -> +4-7% regime).
// q,k: (B,H,T,D); v: (B,H,D,T); y: (B,T,C).
__global__ __launch_bounds__(256, 3)
void attn(const unsigned short* __restrict__ qbuf,
          const unsigned short* __restrict__ kbuf,
          const unsigned short* __restrict__ vT,
          unsigned short* __restrict__ yb) {
  __shared__ __align__(16) unsigned short Ks[3][4096];
  __shared__ __align__(16) unsigned short Vs[3][4096];
  const int tid = threadIdx.x, wave = tid >> 6, lane = tid & 63;
  const int quad = lane >> 4, lr = lane & 15;
  const int bh = blockIdx.x;                  // heads fastest: bh%8 pins XCD
  const int qt = 31 - (int)blockIdx.y;        // heavy-first for refill (LPT)
  const int qrow0 = qt * 64;                  // tile base (head-local)

  const unsigned short* qp0 = qbuf + (size_t)bh * 131072;
  const unsigned short* kp0 = kbuf + (size_t)bh * 131072;
  const unsigned short* vp0 = vT   + (size_t)bh * 131072;

  // Q fragments (B-operand of S^T: n = q = lane&15, k = d = quad*8+j)
  short8 aq[2];
  {
    const unsigned short* qp =
        qp0 + (size_t)(qrow0 + wave * 16 + lr) * 64 + quad * 8;
    aq[0] = *(const short8*)qp;
    aq[1] = *(const short8*)(qp + 32);
  }

  short4v ones4;
#pragma unroll
  for (int i = 0; i < 4; ++i) ones4[i] = (short)0x3F80;  // bf16 1.0

  // DMA staging: thread t -> (row=t>>3 in 0..31 (+32), cg=(t&7)^(row&7))
  const int sr = tid >> 3;
  const int scg = (tid & 7) ^ (sr & 7);
  // K fragment bases (A-operand: m = key = lr (+jt*16), k = d = (quad+4h)*8), swizzled
  int kbase[2];
#pragma unroll
  for (int h = 0; h < 2; ++h)
    kbase[h] = lr * 64 + (((quad + 4 * h) ^ (lr & 7)) << 3);
  // V b64 bases per key-block kb: element (row = d = lr (+jd*16), col = kb*16+quad*4)
  int vbase[4];
#pragma unroll
  for (int kb = 0; kb < 4; ++kb)
    vbase[kb] = lr * 64 + (((2 * kb + (quad >> 1)) ^ (lr & 7)) << 3) + (quad & 1) * 4;

  f32x4 o[4] = {};
  f32x4 lacc = {};

  auto stage = [&](int buf, int kt) {
    const unsigned short* kg = kp0 + (size_t)(kt * 64 + sr) * 64 + scg * 8;
    const unsigned short* vg = vp0 + (size_t)sr * 2048 + kt * 64 + scg * 8;
    gl2lds16(kg,             &Ks[buf][wave * 512]);
    gl2lds16(kg + 32 * 64,   &Ks[buf][2048 + wave * 512]);
    gl2lds16(vg,             &Vs[buf][wave * 512]);
    gl2lds16(vg + 32 * 2048, &Vs[buf][2048 + wave * 512]);
  };

  const int dlast = qt;           // diagonal k-tile index == last tile
  stage(0, 0);
  if (dlast >= 1) stage(1, 1);
  int buf = 0;
  for (int kt = 0; kt <= dlast; ++kt) {
    // Drain own DMAs for tile kt (issued 2 iters ago) but keep the newest
    // stage (4 instrs, tile kt+1) in flight. Each wave drains its own; the
    // barrier then guarantees all waves' contributions to tile kt are in LDS.
    if (kt < dlast) __builtin_amdgcn_s_waitcnt(0x0F74);  // vmcnt(4)
    else            __builtin_amdgcn_s_waitcnt(0x0F70);  // vmcnt(0)
    __builtin_amdgcn_s_barrier();
    if (kt + 2 <= dlast) {
      int nb = buf + 2; if (nb >= 3) nb -= 3;
      stage(nb, kt + 2);          // overwrites buffer of tile kt-1 (consumed)
    }
    const unsigned short* Kb = Ks[buf];
    const unsigned short* Vb = Vs[buf];
    short8 bk[4][2];
#pragma unroll
    for (int jt = 0; jt < 4; ++jt) {
      bk[jt][0] = *(const short8*)(Kb + jt * 1024 + kbase[0]);
      bk[jt][1] = *(const short8*)(Kb + jt * 1024 + kbase[1]);
    }
    // S^T, exp2 (+causal mask on the diagonal tile), pack; lsum.
    f32x4 s[4] = {};
    __builtin_amdgcn_s_setprio(1);
#pragma unroll
    for (int jt = 0; jt < 4; ++jt) {
      s[jt] = MFMA16(bk[jt][0], aq[0], s[jt]);
      s[jt] = MFMA16(bk[jt][1], aq[1], s[jt]);
    }
    __builtin_amdgcn_s_setprio(0);
    short4v pa[4];
    if (kt == dlast) {            // diagonal: key-local > wave*16+lr masked
      const int qloc = wave * 16 + lr;
#pragma unroll
      for (int jt = 0; jt < 4; ++jt) {
        float p[4];
#pragma unroll
        for (int r = 0; r < 4; ++r) {
          p[r] = __builtin_amdgcn_exp2f(s[jt][r]);
          if (jt * 16 + quad * 4 + r > qloc) p[r] = 0.f;
        }
        pa[jt] = pack_bf16x4(p[0], p[1], p[2], p[3]);
      }
    } else {
#pragma unroll
      for (int jt = 0; jt < 4; ++jt) {
        float p[4];
#pragma unroll
        for (int r = 0; r < 4; ++r) p[r] = __builtin_amdgcn_exp2f(s[jt][r]);
        pa[jt] = pack_bf16x4(p[0], p[1], p[2], p[3]);
      }
    }
    __builtin_amdgcn_s_setprio(1);
#pragma unroll
    for (int kb = 0; kb < 4; ++kb)
      lacc = MFMA16K16(ones4, pa[kb], lacc);
    // O += P * V : V b64 reads.
#pragma unroll
    for (int kb = 0; kb < 4; ++kb)
#pragma unroll
      for (int jd = 0; jd < 4; ++jd) {
        const short4v bv = *(const short4v*)(Vb + jd * 1024 + vbase[kb]);
        o[jd] = MFMA16K16(pa[kb], bv, o[jd]);
      }
    __builtin_amdgcn_s_setprio(0);
    buf += 1; if (buf >= 3) buf -= 3;
  }

  // lacc: D[m][q] all-rows-equal = lsum[q = lane&15]; redistribute to rows
  const int b = bh >> 4, h = bh & 15;
  float inv[4];
#pragma unroll
  for (int r = 0; r < 4; ++r)
    inv[r] = __builtin_amdgcn_rcpf(__shfl(lacc[0], quad * 4 + r));
#pragma unroll
  for (int jd = 0; jd < 4; ++jd)
#pragma unroll
    for (int r = 0; r < 4; ++r) {
      const int t = qrow0 + wave * 16 + quad * 4 + r;
      yb[((size_t)b * 2048 + t) * 1024 + h * 64 + jd * 16 + lr] =
          f2bf(o[jd][r] * inv[r]);
    }
}

extern "C" void kernel_launch(void* const* d_in, const int* in_sizes, int n_in,
                              void* d_out, int out_size, void* d_ws, size_t ws_size,
                              hipStream_t stream) {
  const float* x     = (const float*)d_in[0];   // (2,2048,1024)
  const float* Wqkv  = (const float*)d_in[1];   // (1024,3072)
  const float* bqkv  = (const float*)d_in[2];   // (3072,)
  const float* Wproj = (const float*)d_in[3];   // (1024,1024)
  const float* bproj = (const float*)d_in[4];   // (1024,)
  float* out = (float*)d_out;                   // (2,2048,1024) fp32

  char* ws = (char*)d_ws;
  unsigned short* xb     = (unsigned short*)(ws);              //  8.0 MB: x bf16 (4096x1024)
  unsigned short* wqkvT  = (unsigned short*)(ws + 8388608);    //  6.0 MB: Wqkv^T bf16 (3072x1024)
  unsigned short* wprojT = (unsigned short*)(ws + 14680064);   //  2.0 MB: Wproj^T bf16 (1024x1024)
  unsigned short* qbuf   = (unsigned short*)(ws + 16777216);   //  8.0 MB: Q (B,H,T,D), pre-scaled
  unsigned short* kbuf   = (unsigned short*)(ws + 25165824);   //  8.0 MB: K (B,H,T,D)
  unsigned short* vTbuf  = (unsigned short*)(ws + 33554432);   //  8.0 MB: V^T (B,H,D,T)
  unsigned short* ybuf   = (unsigned short*)(ws + 41943040);   //  8.0 MB: y (B,T,C) bf16

  prep<<<5120, 256, 0, stream>>>(x, xb, Wqkv, wqkvT, Wproj, wprojT);
  gemm_bt<0, 128><<<dim3(24, 32), 256, 0, stream>>>(xb, wqkvT, bqkv, nullptr,
                                                    qbuf, kbuf, vTbuf, 3072, 1024);
  attn<<<dim3(32, 32), 256, 0, stream>>>(qbuf, kbuf, vTbuf, ybuf);
  gemm_bt<1, 64><<<dim3(8, 64), 256, 0, stream>>>(ybuf, wprojT, bproj, out,
                                                  nullptr, nullptr, nullptr, 1024, 1024);
}

// Round 6
// 193.991 us; speedup vs baseline: 1.1082x; 1.1082x over previous
//
#include <hip/hip_runtime.h>

// CausalSelfAttention on MI355X (gfx950), bf16 MFMA pipeline.
// B=2 T=2048 C=1024 NH=16 HD=64.  M=B*T=4096.
//
// R17: post-mortem of R16 — the runtime `vsec` branch inside the K-loop kept
// BOTH MFMA operand orders live in the unrolled body: VGPR 80->132, occupancy
// 28->10.8%, QKV gemm 47.6->88.4 us.  The epilogue fix itself worked
// (WRITE_SIZE 40.9 -> 24.0 MB logical, refcheck passed).  Fix: operand order
// is now a COMPILE-TIME template param; QKV is split into two dispatches:
//   gemm_bt<0,128,1> grid(16,32): q/k sections, swapped MFMA(b,a) ->
//       thread holds 4 consecutive d -> 8-B short4v stores into (B,H,T,D)
//   gemm_bt<0,128,0> grid(8,32) n_base=2048: v section, original order ->
//       4 consecutive t -> short4v stores into V^T (B,H,D,T)
// Each instantiation compiles ONE order: no branch, VGPR ~80, 3 blocks/CU.

typedef __attribute__((ext_vector_type(8))) short short8;   // 8 x bf16 (4 VGPR)
typedef __attribute__((ext_vector_type(4))) short short4v;  // 4 x bf16 (2 VGPR, align 8)
typedef __attribute__((ext_vector_type(4))) float f32x4;    // MFMA 16x16 acc
typedef __attribute__((ext_vector_type(2))) unsigned int u32x2;

#define MFMA16(a, b, c) __builtin_amdgcn_mfma_f32_16x16x32_bf16((a), (b), (c), 0, 0, 0)
#define MFMA16K16(a, b, c) __builtin_amdgcn_mfma_f32_16x16x16bf16_1k((a), (b), (c), 0, 0, 0)

__device__ __forceinline__ unsigned short f2bf(float f) {
  unsigned u = __builtin_bit_cast(unsigned, f);
  u += 0x7fffu + ((u >> 16) & 1u);   // RNE
  return (unsigned short)(u >> 16);
}

__device__ __forceinline__ unsigned short f2bf_fast(float f) {
  // round-half-up: cheaper (2 VALU); |err| <= 2^-9 rel, fine for P/y
  return (unsigned short)((__builtin_bit_cast(unsigned, f) + 0x8000u) >> 16);
}

#if __has_builtin(__builtin_amdgcn_cvt_pk_bf16_f32)
typedef __attribute__((ext_vector_type(2))) __bf16 bf16x2;
__device__ __forceinline__ short4v pack_bf16x4(float a, float b, float c, float d) {
  bf16x2 lo = __builtin_amdgcn_cvt_pk_bf16_f32(a, b);
  bf16x2 hi = __builtin_amdgcn_cvt_pk_bf16_f32(c, d);
  u32x2 t;
  t[0] = __builtin_bit_cast(unsigned, lo);
  t[1] = __builtin_bit_cast(unsigned, hi);
  return __builtin_bit_cast(short4v, t);
}
#else
__device__ __forceinline__ short4v pack_bf16x4(float a, float b, float c, float d) {
  short4v r;
  r[0] = (short)f2bf_fast(a); r[1] = (short)f2bf_fast(b);
  r[2] = (short)f2bf_fast(c); r[3] = (short)f2bf_fast(d);
  return r;
}
#endif

__device__ __forceinline__ short4v pack_rne4(float a, float b, float c, float d) {
  short4v r;
  r[0] = (short)f2bf(a); r[1] = (short)f2bf(b);
  r[2] = (short)f2bf(c); r[3] = (short)f2bf(d);
  return r;
}

__device__ __forceinline__ void gl2lds16(const void* g, void* l) {
  // async global->LDS, 16B/lane; LDS dest = wave-uniform base + lane*16
  __builtin_amdgcn_global_load_lds(
      (__attribute__((address_space(1))) void*)g,
      (__attribute__((address_space(3))) void*)l,
      16, 0, 0);
}

// ---------------- merged prep: x->bf16 + both weight transposes ----------------
// blocks [0,4096): conv x (4096x1024 fp32 -> bf16)
// blocks [4096,4864): Wqkv (1024x3072) -> Wqkv^T bf16 (3072x1024), 48x16 tiles
// blocks [4864,5120): Wproj (1024x1024) -> Wproj^T bf16, 16x16 tiles
// Branch is block-uniform, so the __syncthreads in the transpose path is safe.
__global__ __launch_bounds__(256)
void prep(const float* __restrict__ x, unsigned short* __restrict__ xb,
          const float* __restrict__ Wqkv, unsigned short* __restrict__ wqkvT,
          const float* __restrict__ Wproj, unsigned short* __restrict__ wprojT) {
  __shared__ float tile[64][65];
  const int bx = blockIdx.x, tid = threadIdx.x;
  if (bx < 4096) {
    const int i = (bx * 256 + tid) * 4;
    float4 f = *(const float4*)(x + i);
    unsigned long long r = (unsigned long long)f2bf(f.x)
        | ((unsigned long long)f2bf(f.y) << 16)
        | ((unsigned long long)f2bf(f.z) << 32)
        | ((unsigned long long)f2bf(f.w) << 48);
    *(unsigned long long*)(xb + i) = r;
    return;
  }
  const float* W;
  unsigned short* WT;
  int n0, k0, N;
  if (bx < 4864) {
    const int idx = bx - 4096;            // 48 x 16 tiles, N=3072
    W = Wqkv; WT = wqkvT; N = 3072;
    n0 = (idx % 48) * 64; k0 = (idx / 48) * 64;
  } else {
    const int idx = bx - 4864;            // 16 x 16 tiles, N=1024
    W = Wproj; WT = wprojT; N = 1024;
    n0 = (idx % 16) * 64; k0 = (idx / 16) * 64;
  }
  const int K = 1024;
  const int c = tid & 63, rbase = tid >> 6;  // 4 rows per pass, 16 passes
#pragma unroll
  for (int i = 0; i < 16; ++i) {
    int r = i * 4 + rbase;
    tile[r][c] = W[(size_t)(k0 + r) * N + n0 + c];
  }
  __syncthreads();
#pragma unroll
  for (int i = 0; i < 16; ++i) {
    int r = i * 4 + rbase;
    WT[(size_t)(n0 + r) * K + k0 + c] = f2bf(tile[c][r]);
  }
}

// ---------------- GEMM: C = A(MxK) * BT(NxK)^T ----------------
// BK=64, XOR-swizzled LDS staging (conflict-free ds_read_b128 fragments).
// MT = M-tile (128 or 64); N-tile fixed 128.  R1 structure (proven best):
// single-buffered 32 KB LDS -> ~3 blocks/CU; stage -> sync -> compute -> sync.
// SWAP template param (compile-time!):
//   SWAP==1: MFMA(b,a) -> thread holds 4 consecutive n at fixed m
//     -> q/k epilogue: short4v (8 B) stores into (B,H,T,D)
//     -> proj epilogue: float4 stores into row-major fp32
//   SWAP==0: MFMA(a,b) -> thread holds 4 consecutive m at fixed n
//     -> v epilogue: short4v stores into V^T (B,H,D,T)
// EPI==0: QKV epilogue (q PRE-SCALED by 0.125*log2(e)); EPI==1: proj.
template <int EPI, int MT, int SWAP>
__global__ __launch_bounds__(256)
void gemm_bt(const unsigned short* __restrict__ A,
             const unsigned short* __restrict__ BT,
             const float* __restrict__ bias,
             float* __restrict__ outF,
             unsigned short* __restrict__ q_out,
             unsigned short* __restrict__ k_out,
             unsigned short* __restrict__ vT_out,
             int Ndim, int Kdim, int n_base) {
  constexpr int IF = MT / 32;                 // A-frags per wave per ksub
  constexpr int RA = MT / 32;                 // A staging rounds (32 rows each)
  __shared__ __align__(16) unsigned short As[MT * 64];
  __shared__ __align__(16) unsigned short Bs[128 * 64];
  const int tid = threadIdx.x;
  const int wave = tid >> 6, lane = tid & 63;
  const int quad = lane >> 4, lr = lane & 15;
  const int wm = wave >> 1, wn = wave & 1;
  const int m0 = blockIdx.y * MT, n0 = blockIdx.x * 128 + n_base;

  const int r_l = tid >> 3;
  const int cg = (tid & 7) ^ (r_l & 7);
  const unsigned short* gA = A + (size_t)(m0 + r_l) * Kdim + cg * 8;
  const unsigned short* gB = BT + (size_t)(n0 + r_l) * Kdim + cg * 8;
  const size_t rstep = (size_t)32 * Kdim;

  f32x4 acc[IF][4] = {};
  for (int k0 = 0; k0 < Kdim; k0 += 64) {
#pragma unroll
    for (int rd = 0; rd < RA; ++rd)
      gl2lds16(gA + k0 + rd * rstep, As + rd * 2048 + wave * 512);
#pragma unroll
    for (int rd = 0; rd < 4; ++rd)
      gl2lds16(gB + k0 + rd * rstep, Bs + rd * 2048 + wave * 512);
    __syncthreads();
#pragma unroll
    for (int s = 0; s < 2; ++s) {
      const int sw = ((s * 4 + quad) ^ (lr & 7)) * 8;
      short8 a[IF], b[4];
#pragma unroll
      for (int i = 0; i < IF; ++i)
        a[i] = *(const short8*)(As + (wm * (MT / 2) + i * 16 + lr) * 64 + sw);
#pragma unroll
      for (int j = 0; j < 4; ++j)
        b[j] = *(const short8*)(Bs + (wn * 64 + j * 16 + lr) * 64 + sw);
#pragma unroll
      for (int i = 0; i < IF; ++i)
#pragma unroll
        for (int j = 0; j < 4; ++j) {
          if constexpr (SWAP)
            acc[i][j] = MFMA16(b[j], a[i], acc[i][j]);
          else
            acc[i][j] = MFMA16(a[i], b[j], acc[i][j]);
        }
    }
    __syncthreads();
  }

  if constexpr (EPI == 0 && SWAP == 0) {
    // v (original order): C[m][n], thread: m = m0+wm*64+quad*4+i*16+{r},
    // n = n0+wn*64+lr+j*16.  Pack 4 m-consecutive (=t) -> V^T (B,H,D,T).
    const int row_t = wm * (MT / 2) + quad * 4;
    const int col_t = wn * 64 + lr;
#pragma unroll
    for (int j = 0; j < 4; ++j) {
      const int n = n0 + col_t + j * 16;
      const float bi = bias[n];
      const int nn = n & 1023, h = nn >> 6, d = nn & 63;
#pragma unroll
      for (int i = 0; i < IF; ++i) {
        const int m_base = m0 + row_t + i * 16;   // 4 consecutive m
        const int bb = m_base >> 11, t0 = m_base & 2047;
        const int bh = bb * 16 + h;
        short4v pk = pack_rne4(acc[i][j][0] + bi, acc[i][j][1] + bi,
                               acc[i][j][2] + bi, acc[i][j][3] + bi);
        *(short4v*)(vT_out + ((size_t)bh * 64 + d) * 2048 + t0) = pk;
      }
    }
  } else if constexpr (EPI == 0) {
    // q/k (swapped): C[m][n], thread: m = m0+wm*64+i*16+lr,
    // n = n0+wn*64+j*16+quad*4+{r}.  Pack 4 n-consecutive (=d) -> (B,H,T,D).
    const int sec = n0 >> 10;                           // 0 = q, 1 = k
    const float scl = (sec == 0) ? 0.18033688f : 1.0f;  // 0.125*log2(e) into Q
    unsigned short* outb = (sec == 0) ? q_out : k_out;
    const int bb = m0 >> 11;                            // block-uniform
    const int hh = ((n0 & 1023) >> 6) + wn;             // wave-uniform head
    unsigned short* dst0 = outb + (size_t)(bb * 16 + hh) * 131072;
#pragma unroll
    for (int j = 0; j < 4; ++j) {
      const int nb = wn * 64 + j * 16 + quad * 4;       // n_loc base
      const float4 bi = *(const float4*)(bias + n0 + nb);
      const int d0 = j * 16 + quad * 4;                 // (nb & 63)
#pragma unroll
      for (int i = 0; i < IF; ++i) {
        const int t0 = (m0 & 2047) + wm * (MT / 2) + i * 16 + lr;
        short4v pk = pack_rne4((acc[i][j][0] + bi.x) * scl,
                               (acc[i][j][1] + bi.y) * scl,
                               (acc[i][j][2] + bi.z) * scl,
                               (acc[i][j][3] + bi.w) * scl);
        *(short4v*)(dst0 + (size_t)t0 * 64 + d0) = pk;
      }
    }
  } else {
    // proj (swapped): float4 store, full-line coalesced across quads
#pragma unroll
    for (int j = 0; j < 4; ++j) {
      const int nb = n0 + wn * 64 + j * 16 + quad * 4;
      const float4 bi = *(const float4*)(bias + nb);
#pragma unroll
      for (int i = 0; i < IF; ++i) {
        const int m = m0 + wm * (MT / 2) + i * 16 + lr;
        float4 o4;
        o4.x = acc[i][j][0] + bi.x;
        o4.y = acc[i][j][1] + bi.y;
        o4.z = acc[i][j][2] + bi.z;
        o4.w = acc[i][j][3] + bi.w;
        *(float4*)(outF + (size_t)m * Ndim + nb) = o4;
      }
    }
  }
}

// ---------------- flash-style causal attention, 64-row q-tiles ----------------
// m=0 softmax; Q PRE-SCALED by 0.125*log2(e) so P = exp2(S).
// Transposed-S trick: S^T = K*Q^T; its C-layout IS the K=16 A-operand layout.
// Block = 4 waves x 16 q-rows = 64 q-rows; K/V fragment LDS reads shared.
// 1024 blocks, heavy-first (LPT) dispatch, bh%8 pins XCD for K/V L2 locality.
// Triple-buffered K/V staged TWO tiles ahead; raw s_barrier + manual
// s_waitcnt vmcnt(4) so the newest stage stays in flight across the barrier.
// T5 s_setprio(1) around MFMA clusters (independent blocks -> +4-7% regime).
// q,k: (B,H,T,D); v: (B,H,D,T); y: (B,T,C).
__global__ __launch_bounds__(256, 3)
void attn(const unsigned short* __restrict__ qbuf,
          const unsigned short* __restrict__ kbuf,
          const unsigned short* __restrict__ vT,
          unsigned short* __restrict__ yb) {
  __shared__ __align__(16) unsigned short Ks[3][4096];
  __shared__ __align__(16) unsigned short Vs[3][4096];
  const int tid = threadIdx.x, wave = tid >> 6, lane = tid & 63;
  const int quad = lane >> 4, lr = lane & 15;
  const int bh = blockIdx.x;                  // heads fastest: bh%8 pins XCD
  const int qt = 31 - (int)blockIdx.y;        // heavy-first for refill (LPT)
  const int qrow0 = qt * 64;                  // tile base (head-local)

  const unsigned short* qp0 = qbuf + (size_t)bh * 131072;
  const unsigned short* kp0 = kbuf + (size_t)bh * 131072;
  const unsigned short* vp0 = vT   + (size_t)bh * 131072;

  // Q fragments (B-operand of S^T: n = q = lane&15, k = d = quad*8+j)
  short8 aq[2];
  {
    const unsigned short* qp =
        qp0 + (size_t)(qrow0 + wave * 16 + lr) * 64 + quad * 8;
    aq[0] = *(const short8*)qp;
    aq[1] = *(const short8*)(qp + 32);
  }

  short4v ones4;
#pragma unroll
  for (int i = 0; i < 4; ++i) ones4[i] = (short)0x3F80;  // bf16 1.0

  // DMA staging: thread t -> (row=t>>3 in 0..31 (+32), cg=(t&7)^(row&7))
  const int sr = tid >> 3;
  const int scg = (tid & 7) ^ (sr & 7);
  // K fragment bases (A-operand: m = key = lr (+jt*16), k = d = (quad+4h)*8), swizzled
  int kbase[2];
#pragma unroll
  for (int h = 0; h < 2; ++h)
    kbase[h] = lr * 64 + (((quad + 4 * h) ^ (lr & 7)) << 3);
  // V b64 bases per key-block kb: element (row = d = lr (+jd*16), col = kb*16+quad*4)
  int vbase[4];
#pragma unroll
  for (int kb = 0; kb < 4; ++kb)
    vbase[kb] = lr * 64 + (((2 * kb + (quad >> 1)) ^ (lr & 7)) << 3) + (quad & 1) * 4;

  f32x4 o[4] = {};
  f32x4 lacc = {};

  auto stage = [&](int buf, int kt) {
    const unsigned short* kg = kp0 + (size_t)(kt * 64 + sr) * 64 + scg * 8;
    const unsigned short* vg = vp0 + (size_t)sr * 2048 + kt * 64 + scg * 8;
    gl2lds16(kg,             &Ks[buf][wave * 512]);
    gl2lds16(kg + 32 * 64,   &Ks[buf][2048 + wave * 512]);
    gl2lds16(vg,             &Vs[buf][wave * 512]);
    gl2lds16(vg + 32 * 2048, &Vs[buf][2048 + wave * 512]);
  };

  const int dlast = qt;           // diagonal k-tile index == last tile
  stage(0, 0);
  if (dlast >= 1) stage(1, 1);
  int buf = 0;
  for (int kt = 0; kt <= dlast; ++kt) {
    // Drain own DMAs for tile kt (issued 2 iters ago) but keep the newest
    // stage (4 instrs, tile kt+1) in flight. Each wave drains its own; the
    // barrier then guarantees all waves' contributions to tile kt are in LDS.
    if (kt < dlast) __builtin_amdgcn_s_waitcnt(0x0F74);  // vmcnt(4)
    else            __builtin_amdgcn_s_waitcnt(0x0F70);  // vmcnt(0)
    __builtin_amdgcn_s_barrier();
    if (kt + 2 <= dlast) {
      int nb = buf + 2; if (nb >= 3) nb -= 3;
      stage(nb, kt + 2);          // overwrites buffer of tile kt-1 (consumed)
    }
    const unsigned short* Kb = Ks[buf];
    const unsigned short* Vb = Vs[buf];
    short8 bk[4][2];
#pragma unroll
    for (int jt = 0; jt < 4; ++jt) {
      bk[jt][0] = *(const short8*)(Kb + jt * 1024 + kbase[0]);
      bk[jt][1] = *(const short8*)(Kb + jt * 1024 + kbase[1]);
    }
    // S^T, exp2 (+causal mask on the diagonal tile), pack; lsum.
    f32x4 s[4] = {};
    __builtin_amdgcn_s_setprio(1);
#pragma unroll
    for (int jt = 0; jt < 4; ++jt) {
      s[jt] = MFMA16(bk[jt][0], aq[0], s[jt]);
      s[jt] = MFMA16(bk[jt][1], aq[1], s[jt]);
    }
    __builtin_amdgcn_s_setprio(0);
    short4v pa[4];
    if (kt == dlast) {            // diagonal: key-local > wave*16+lr masked
      const int qloc = wave * 16 + lr;
#pragma unroll
      for (int jt = 0; jt < 4; ++jt) {
        float p[4];
#pragma unroll
        for (int r = 0; r < 4; ++r) {
          p[r] = __builtin_amdgcn_exp2f(s[jt][r]);
          if (jt * 16 + quad * 4 + r > qloc) p[r] = 0.f;
        }
        pa[jt] = pack_bf16x4(p[0], p[1], p[2], p[3]);
      }
    } else {
#pragma unroll
      for (int jt = 0; jt < 4; ++jt) {
        float p[4];
#pragma unroll
        for (int r = 0; r < 4; ++r) p[r] = __builtin_amdgcn_exp2f(s[jt][r]);
        pa[jt] = pack_bf16x4(p[0], p[1], p[2], p[3]);
      }
    }
    __builtin_amdgcn_s_setprio(1);
#pragma unroll
    for (int kb = 0; kb < 4; ++kb)
      lacc = MFMA16K16(ones4, pa[kb], lacc);
    // O += P * V : V b64 reads.
#pragma unroll
    for (int kb = 0; kb < 4; ++kb)
#pragma unroll
      for (int jd = 0; jd < 4; ++jd) {
        const short4v bv = *(const short4v*)(Vb + jd * 1024 + vbase[kb]);
        o[jd] = MFMA16K16(pa[kb], bv, o[jd]);
      }
    __builtin_amdgcn_s_setprio(0);
    buf += 1; if (buf >= 3) buf -= 3;
  }

  // lacc: D[m][q] all-rows-equal = lsum[q = lane&15]; redistribute to rows
  const int b = bh >> 4, h = bh & 15;
  float inv[4];
#pragma unroll
  for (int r = 0; r < 4; ++r)
    inv[r] = __builtin_amdgcn_rcpf(__shfl(lacc[0], quad * 4 + r));
#pragma unroll
  for (int jd = 0; jd < 4; ++jd)
#pragma unroll
    for (int r = 0; r < 4; ++r) {
      const int t = qrow0 + wave * 16 + quad * 4 + r;
      yb[((size_t)b * 2048 + t) * 1024 + h * 64 + jd * 16 + lr] =
          f2bf(o[jd][r] * inv[r]);
    }
}

extern "C" void kernel_launch(void* const* d_in, const int* in_sizes, int n_in,
                              void* d_out, int out_size, void* d_ws, size_t ws_size,
                              hipStream_t stream) {
  const float* x     = (const float*)d_in[0];   // (2,2048,1024)
  const float* Wqkv  = (const float*)d_in[1];   // (1024,3072)
  const float* bqkv  = (const float*)d_in[2];   // (3072,)
  const float* Wproj = (const float*)d_in[3];   // (1024,1024)
  const float* bproj = (const float*)d_in[4];   // (1024,)
  float* out = (float*)d_out;                   // (2,2048,1024) fp32

  char* ws = (char*)d_ws;
  unsigned short* xb     = (unsigned short*)(ws);              //  8.0 MB: x bf16 (4096x1024)
  unsigned short* wqkvT  = (unsigned short*)(ws + 8388608);    //  6.0 MB: Wqkv^T bf16 (3072x1024)
  unsigned short* wprojT = (unsigned short*)(ws + 14680064);   //  2.0 MB: Wproj^T bf16 (1024x1024)
  unsigned short* qbuf   = (unsigned short*)(ws + 16777216);   //  8.0 MB: Q (B,H,T,D), pre-scaled
  unsigned short* kbuf   = (unsigned short*)(ws + 25165824);   //  8.0 MB: K (B,H,T,D)
  unsigned short* vTbuf  = (unsigned short*)(ws + 33554432);   //  8.0 MB: V^T (B,H,D,T)
  unsigned short* ybuf   = (unsigned short*)(ws + 41943040);   //  8.0 MB: y (B,T,C) bf16

  prep<<<5120, 256, 0, stream>>>(x, xb, Wqkv, wqkvT, Wproj, wprojT);
  gemm_bt<0, 128, 1><<<dim3(16, 32), 256, 0, stream>>>(xb, wqkvT, bqkv, nullptr,
                                                       qbuf, kbuf, vTbuf, 3072, 1024, 0);
  gemm_bt<0, 128, 0><<<dim3(8, 32), 256, 0, stream>>>(xb, wqkvT, bqkv, nullptr,
                                                      qbuf, kbuf, vTbuf, 3072, 1024, 2048);
  attn<<<dim3(32, 32), 256, 0, stream>>>(qbuf, kbuf, vTbuf, ybuf);
  gemm_bt<1, 64, 1><<<dim3(8, 64), 256, 0, stream>>>(ybuf, wprojT, bproj, out,
                                                     nullptr, nullptr, nullptr, 1024, 1024, 0);
}

// Round 7
// 186.200 us; speedup vs baseline: 1.1546x; 1.0418x over previous
//
#include <hip/hip_runtime.h>

// CausalSelfAttention on MI355X (gfx950), bf16 MFMA pipeline.
// B=2 T=2048 C=1024 NH=16 HD=64.  M=B*T=4096.
//
// R18: post-mortem of R17 — splitting QKV into two dispatches cost ~17 us:
// q/k gemm got 2 blocks/CU and v gemm 1 block/CU (the R2/R3-proven-fatal
// regime: cross-block TLP is this structure's latency hiding).  Fix:
// recombine into ONE 768-block dispatch with a TOP-LEVEL block-uniform
// branch into two fully self-contained paths (own K-loop, own acc, own
// epilogue).  Unlike R16's per-MFMA runtime branch (both orders live in one
// unrolled body -> VGPR 132), disjoint paths let regalloc reuse registers:
// VGPR ~= max(paths).  gemm_core<SWAP> is forceinline-templated so each
// path compiles exactly one MFMA operand order.
//   SWAP=1 (q/k, proj): MFMA(b,a) -> 4 consecutive n per thread ->
//     8-B short4v stores into (B,H,T,D) / float4 stores for proj
//   SWAP=0 (v): MFMA(a,b) -> 4 consecutive m per thread ->
//     short4v stores into V^T (B,H,D,T)

typedef __attribute__((ext_vector_type(8))) short short8;   // 8 x bf16 (4 VGPR)
typedef __attribute__((ext_vector_type(4))) short short4v;  // 4 x bf16 (2 VGPR, align 8)
typedef __attribute__((ext_vector_type(4))) float f32x4;    // MFMA 16x16 acc
typedef __attribute__((ext_vector_type(2))) unsigned int u32x2;

#define MFMA16(a, b, c) __builtin_amdgcn_mfma_f32_16x16x32_bf16((a), (b), (c), 0, 0, 0)
#define MFMA16K16(a, b, c) __builtin_amdgcn_mfma_f32_16x16x16bf16_1k((a), (b), (c), 0, 0, 0)

__device__ __forceinline__ unsigned short f2bf(float f) {
  unsigned u = __builtin_bit_cast(unsigned, f);
  u += 0x7fffu + ((u >> 16) & 1u);   // RNE
  return (unsigned short)(u >> 16);
}

__device__ __forceinline__ unsigned short f2bf_fast(float f) {
  // round-half-up: cheaper (2 VALU); |err| <= 2^-9 rel, fine for P/y
  return (unsigned short)((__builtin_bit_cast(unsigned, f) + 0x8000u) >> 16);
}

#if __has_builtin(__builtin_amdgcn_cvt_pk_bf16_f32)
typedef __attribute__((ext_vector_type(2))) __bf16 bf16x2;
__device__ __forceinline__ short4v pack_bf16x4(float a, float b, float c, float d) {
  bf16x2 lo = __builtin_amdgcn_cvt_pk_bf16_f32(a, b);
  bf16x2 hi = __builtin_amdgcn_cvt_pk_bf16_f32(c, d);
  u32x2 t;
  t[0] = __builtin_bit_cast(unsigned, lo);
  t[1] = __builtin_bit_cast(unsigned, hi);
  return __builtin_bit_cast(short4v, t);
}
#else
__device__ __forceinline__ short4v pack_bf16x4(float a, float b, float c, float d) {
  short4v r;
  r[0] = (short)f2bf_fast(a); r[1] = (short)f2bf_fast(b);
  r[2] = (short)f2bf_fast(c); r[3] = (short)f2bf_fast(d);
  return r;
}
#endif

__device__ __forceinline__ short4v pack_rne4(float a, float b, float c, float d) {
  short4v r;
  r[0] = (short)f2bf(a); r[1] = (short)f2bf(b);
  r[2] = (short)f2bf(c); r[3] = (short)f2bf(d);
  return r;
}

__device__ __forceinline__ void gl2lds16(const void* g, void* l) {
  // async global->LDS, 16B/lane; LDS dest = wave-uniform base + lane*16
  __builtin_amdgcn_global_load_lds(
      (__attribute__((address_space(1))) void*)g,
      (__attribute__((address_space(3))) void*)l,
      16, 0, 0);
}

// ---------------- merged prep: x->bf16 + both weight transposes ----------------
// blocks [0,4096): conv x (4096x1024 fp32 -> bf16)
// blocks [4096,4864): Wqkv (1024x3072) -> Wqkv^T bf16 (3072x1024), 48x16 tiles
// blocks [4864,5120): Wproj (1024x1024) -> Wproj^T bf16, 16x16 tiles
// Branch is block-uniform, so the __syncthreads in the transpose path is safe.
__global__ __launch_bounds__(256)
void prep(const float* __restrict__ x, unsigned short* __restrict__ xb,
          const float* __restrict__ Wqkv, unsigned short* __restrict__ wqkvT,
          const float* __restrict__ Wproj, unsigned short* __restrict__ wprojT) {
  __shared__ float tile[64][65];
  const int bx = blockIdx.x, tid = threadIdx.x;
  if (bx < 4096) {
    const int i = (bx * 256 + tid) * 4;
    float4 f = *(const float4*)(x + i);
    unsigned long long r = (unsigned long long)f2bf(f.x)
        | ((unsigned long long)f2bf(f.y) << 16)
        | ((unsigned long long)f2bf(f.z) << 32)
        | ((unsigned long long)f2bf(f.w) << 48);
    *(unsigned long long*)(xb + i) = r;
    return;
  }
  const float* W;
  unsigned short* WT;
  int n0, k0, N;
  if (bx < 4864) {
    const int idx = bx - 4096;            // 48 x 16 tiles, N=3072
    W = Wqkv; WT = wqkvT; N = 3072;
    n0 = (idx % 48) * 64; k0 = (idx / 48) * 64;
  } else {
    const int idx = bx - 4864;            // 16 x 16 tiles, N=1024
    W = Wproj; WT = wprojT; N = 1024;
    n0 = (idx % 16) * 64; k0 = (idx / 16) * 64;
  }
  const int K = 1024;
  const int c = tid & 63, rbase = tid >> 6;  // 4 rows per pass, 16 passes
#pragma unroll
  for (int i = 0; i < 16; ++i) {
    int r = i * 4 + rbase;
    tile[r][c] = W[(size_t)(k0 + r) * N + n0 + c];
  }
  __syncthreads();
#pragma unroll
  for (int i = 0; i < 16; ++i) {
    int r = i * 4 + rbase;
    WT[(size_t)(n0 + r) * K + k0 + c] = f2bf(tile[c][r]);
  }
}

// ---------------- GEMM core: staging + MFMA loop (templated operand order) ----
// R1 structure: single-buffered 32 KB LDS -> ~3 blocks/CU; stage -> sync ->
// compute -> sync; cross-block TLP hides the drain.
template <int SWAP, int MT>
__device__ __forceinline__ void gemm_core(
    const unsigned short* __restrict__ gA,
    const unsigned short* __restrict__ gB,
    unsigned short* As, unsigned short* Bs,
    int Kdim, int wave, int quad, int lr, int wm, int wn,
    f32x4 (&acc)[MT / 32][4]) {
  constexpr int IF = MT / 32;
  constexpr int RA = MT / 32;
  const size_t rstep = (size_t)32 * Kdim;
  for (int k0 = 0; k0 < Kdim; k0 += 64) {
#pragma unroll
    for (int rd = 0; rd < RA; ++rd)
      gl2lds16(gA + k0 + rd * rstep, As + rd * 2048 + wave * 512);
#pragma unroll
    for (int rd = 0; rd < 4; ++rd)
      gl2lds16(gB + k0 + rd * rstep, Bs + rd * 2048 + wave * 512);
    __syncthreads();
#pragma unroll
    for (int s = 0; s < 2; ++s) {
      const int sw = ((s * 4 + quad) ^ (lr & 7)) * 8;
      short8 a[IF], b[4];
#pragma unroll
      for (int i = 0; i < IF; ++i)
        a[i] = *(const short8*)(As + (wm * (MT / 2) + i * 16 + lr) * 64 + sw);
#pragma unroll
      for (int j = 0; j < 4; ++j)
        b[j] = *(const short8*)(Bs + (wn * 64 + j * 16 + lr) * 64 + sw);
#pragma unroll
      for (int i = 0; i < IF; ++i)
#pragma unroll
        for (int j = 0; j < 4; ++j) {
          if constexpr (SWAP)
            acc[i][j] = MFMA16(b[j], a[i], acc[i][j]);
          else
            acc[i][j] = MFMA16(a[i], b[j], acc[i][j]);
        }
    }
    __syncthreads();
  }
}

// ---------------- GEMM kernel: C = A(MxK) * BT(NxK)^T ----------------
// EPI==0: QKV (one dispatch, 768 blocks).  Block-uniform top-level branch:
//   n0 < 2048  -> q/k path (SWAP=1), short4v stores into (B,H,T,D);
//                 q PRE-SCALED by 0.125*log2(e)
//   n0 >= 2048 -> v path (SWAP=0), short4v stores into V^T (B,H,D,T)
// EPI==1: proj path (SWAP=1), float4 stores + bias.
template <int EPI, int MT>
__global__ __launch_bounds__(256)
void gemm_bt(const unsigned short* __restrict__ A,
             const unsigned short* __restrict__ BT,
             const float* __restrict__ bias,
             float* __restrict__ outF,
             unsigned short* __restrict__ q_out,
             unsigned short* __restrict__ k_out,
             unsigned short* __restrict__ vT_out,
             int Ndim, int Kdim) {
  constexpr int IF = MT / 32;
  __shared__ __align__(16) unsigned short As[MT * 64];
  __shared__ __align__(16) unsigned short Bs[128 * 64];
  const int tid = threadIdx.x;
  const int wave = tid >> 6, lane = tid & 63;
  const int quad = lane >> 4, lr = lane & 15;
  const int wm = wave >> 1, wn = wave & 1;
  const int m0 = blockIdx.y * MT, n0 = blockIdx.x * 128;

  const int r_l = tid >> 3;
  const int cg = (tid & 7) ^ (r_l & 7);
  const unsigned short* gA = A + (size_t)(m0 + r_l) * Kdim + cg * 8;
  const unsigned short* gB = BT + (size_t)(n0 + r_l) * Kdim + cg * 8;

  if constexpr (EPI == 1) {
    f32x4 acc[IF][4] = {};
    gemm_core<1, MT>(gA, gB, As, Bs, Kdim, wave, quad, lr, wm, wn, acc);
    // proj (swapped): float4 store, full-line coalesced across quads
#pragma unroll
    for (int j = 0; j < 4; ++j) {
      const int nb = n0 + wn * 64 + j * 16 + quad * 4;
      const float4 bi = *(const float4*)(bias + nb);
#pragma unroll
      for (int i = 0; i < IF; ++i) {
        const int m = m0 + wm * (MT / 2) + i * 16 + lr;
        float4 o4;
        o4.x = acc[i][j][0] + bi.x;
        o4.y = acc[i][j][1] + bi.y;
        o4.z = acc[i][j][2] + bi.z;
        o4.w = acc[i][j][3] + bi.w;
        *(float4*)(outF + (size_t)m * Ndim + nb) = o4;
      }
    }
  } else if (n0 >= 2048) {
    // ---- v path (original order): 4 consecutive m (=t) -> V^T (B,H,D,T)
    f32x4 acc[IF][4] = {};
    gemm_core<0, MT>(gA, gB, As, Bs, Kdim, wave, quad, lr, wm, wn, acc);
    const int row_t = wm * (MT / 2) + quad * 4;
    const int col_t = wn * 64 + lr;
#pragma unroll
    for (int j = 0; j < 4; ++j) {
      const int n = n0 + col_t + j * 16;
      const float bi = bias[n];
      const int nn = n & 1023, h = nn >> 6, d = nn & 63;
#pragma unroll
      for (int i = 0; i < IF; ++i) {
        const int m_base = m0 + row_t + i * 16;   // 4 consecutive m
        const int bb = m_base >> 11, t0 = m_base & 2047;
        const int bh = bb * 16 + h;
        short4v pk = pack_rne4(acc[i][j][0] + bi, acc[i][j][1] + bi,
                               acc[i][j][2] + bi, acc[i][j][3] + bi);
        *(short4v*)(vT_out + ((size_t)bh * 64 + d) * 2048 + t0) = pk;
      }
    }
  } else {
    // ---- q/k path (swapped): 4 consecutive n (=d) -> (B,H,T,D)
    f32x4 acc[IF][4] = {};
    gemm_core<1, MT>(gA, gB, As, Bs, Kdim, wave, quad, lr, wm, wn, acc);
    const int sec = n0 >> 10;                           // 0 = q, 1 = k
    const float scl = (sec == 0) ? 0.18033688f : 1.0f;  // 0.125*log2(e) into Q
    unsigned short* outb = (sec == 0) ? q_out : k_out;
    const int bb = m0 >> 11;                            // block-uniform
    const int hh = ((n0 & 1023) >> 6) + wn;             // wave-uniform head
    unsigned short* dst0 = outb + (size_t)(bb * 16 + hh) * 131072;
#pragma unroll
    for (int j = 0; j < 4; ++j) {
      const int nb = wn * 64 + j * 16 + quad * 4;       // n_loc base
      const float4 bi = *(const float4*)(bias + n0 + nb);
      const int d0 = j * 16 + quad * 4;                 // (nb & 63)
#pragma unroll
      for (int i = 0; i < IF; ++i) {
        const int t0 = (m0 & 2047) + wm * (MT / 2) + i * 16 + lr;
        short4v pk = pack_rne4((acc[i][j][0] + bi.x) * scl,
                               (acc[i][j][1] + bi.y) * scl,
                               (acc[i][j][2] + bi.z) * scl,
                               (acc[i][j][3] + bi.w) * scl);
        *(short4v*)(dst0 + (size_t)t0 * 64 + d0) = pk;
      }
    }
  }
}

// ---------------- flash-style causal attention, 64-row q-tiles ----------------
// m=0 softmax; Q PRE-SCALED by 0.125*log2(e) so P = exp2(S).
// Transposed-S trick: S^T = K*Q^T; its C-layout IS the K=16 A-operand layout.
// Block = 4 waves x 16 q-rows = 64 q-rows; K/V fragment LDS reads shared.
// 1024 blocks, heavy-first (LPT) dispatch, bh%8 pins XCD for K/V L2 locality.
// Triple-buffered K/V staged TWO tiles ahead; raw s_barrier + manual
// s_waitcnt vmcnt(4) so the newest stage stays in flight across the barrier.
// T5 s_setprio(1) around MFMA clusters (independent blocks -> +4-7% regime).
// q,k: (B,H,T,D); v: (B,H,D,T); y: (B,T,C).
__global__ __launch_bounds__(256, 3)
void attn(const unsigned short* __restrict__ qbuf,
          const unsigned short* __restrict__ kbuf,
          const unsigned short* __restrict__ vT,
          unsigned short* __restrict__ yb) {
  __shared__ __align__(16) unsigned short Ks[3][4096];
  __shared__ __align__(16) unsigned short Vs[3][4096];
  const int tid = threadIdx.x, wave = tid >> 6, lane = tid & 63;
  const int quad = lane >> 4, lr = lane & 15;
  const int bh = blockIdx.x;                  // heads fastest: bh%8 pins XCD
  const int qt = 31 - (int)blockIdx.y;        // heavy-first for refill (LPT)
  const int qrow0 = qt * 64;                  // tile base (head-local)

  const unsigned short* qp0 = qbuf + (size_t)bh * 131072;
  const unsigned short* kp0 = kbuf + (size_t)bh * 131072;
  const unsigned short* vp0 = vT   + (size_t)bh * 131072;

  // Q fragments (B-operand of S^T: n = q = lane&15, k = d = quad*8+j)
  short8 aq[2];
  {
    const unsigned short* qp =
        qp0 + (size_t)(qrow0 + wave * 16 + lr) * 64 + quad * 8;
    aq[0] = *(const short8*)qp;
    aq[1] = *(const short8*)(qp + 32);
  }

  short4v ones4;
#pragma unroll
  for (int i = 0; i < 4; ++i) ones4[i] = (short)0x3F80;  // bf16 1.0

  // DMA staging: thread t -> (row=t>>3 in 0..31 (+32), cg=(t&7)^(row&7))
  const int sr = tid >> 3;
  const int scg = (tid & 7) ^ (sr & 7);
  // K fragment bases (A-operand: m = key = lr (+jt*16), k = d = (quad+4h)*8), swizzled
  int kbase[2];
#pragma unroll
  for (int h = 0; h < 2; ++h)
    kbase[h] = lr * 64 + (((quad + 4 * h) ^ (lr & 7)) << 3);
  // V b64 bases per key-block kb: element (row = d = lr (+jd*16), col = kb*16+quad*4)
  int vbase[4];
#pragma unroll
  for (int kb = 0; kb < 4; ++kb)
    vbase[kb] = lr * 64 + (((2 * kb + (quad >> 1)) ^ (lr & 7)) << 3) + (quad & 1) * 4;

  f32x4 o[4] = {};
  f32x4 lacc = {};

  auto stage = [&](int buf, int kt) {
    const unsigned short* kg = kp0 + (size_t)(kt * 64 + sr) * 64 + scg * 8;
    const unsigned short* vg = vp0 + (size_t)sr * 2048 + kt * 64 + scg * 8;
    gl2lds16(kg,             &Ks[buf][wave * 512]);
    gl2lds16(kg + 32 * 64,   &Ks[buf][2048 + wave * 512]);
    gl2lds16(vg,             &Vs[buf][wave * 512]);
    gl2lds16(vg + 32 * 2048, &Vs[buf][2048 + wave * 512]);
  };

  const int dlast = qt;           // diagonal k-tile index == last tile
  stage(0, 0);
  if (dlast >= 1) stage(1, 1);
  int buf = 0;
  for (int kt = 0; kt <= dlast; ++kt) {
    // Drain own DMAs for tile kt (issued 2 iters ago) but keep the newest
    // stage (4 instrs, tile kt+1) in flight. Each wave drains its own; the
    // barrier then guarantees all waves' contributions to tile kt are in LDS.
    if (kt < dlast) __builtin_amdgcn_s_waitcnt(0x0F74);  // vmcnt(4)
    else            __builtin_amdgcn_s_waitcnt(0x0F70);  // vmcnt(0)
    __builtin_amdgcn_s_barrier();
    if (kt + 2 <= dlast) {
      int nb = buf + 2; if (nb >= 3) nb -= 3;
      stage(nb, kt + 2);          // overwrites buffer of tile kt-1 (consumed)
    }
    const unsigned short* Kb = Ks[buf];
    const unsigned short* Vb = Vs[buf];
    short8 bk[4][2];
#pragma unroll
    for (int jt = 0; jt < 4; ++jt) {
      bk[jt][0] = *(const short8*)(Kb + jt * 1024 + kbase[0]);
      bk[jt][1] = *(const short8*)(Kb + jt * 1024 + kbase[1]);
    }
    // S^T, exp2 (+causal mask on the diagonal tile), pack; lsum.
    f32x4 s[4] = {};
    __builtin_amdgcn_s_setprio(1);
#pragma unroll
    for (int jt = 0; jt < 4; ++jt) {
      s[jt] = MFMA16(bk[jt][0], aq[0], s[jt]);
      s[jt] = MFMA16(bk[jt][1], aq[1], s[jt]);
    }
    __builtin_amdgcn_s_setprio(0);
    short4v pa[4];
    if (kt == dlast) {            // diagonal: key-local > wave*16+lr masked
      const int qloc = wave * 16 + lr;
#pragma unroll
      for (int jt = 0; jt < 4; ++jt) {
        float p[4];
#pragma unroll
        for (int r = 0; r < 4; ++r) {
          p[r] = __builtin_amdgcn_exp2f(s[jt][r]);
          if (jt * 16 + quad * 4 + r > qloc) p[r] = 0.f;
        }
        pa[jt] = pack_bf16x4(p[0], p[1], p[2], p[3]);
      }
    } else {
#pragma unroll
      for (int jt = 0; jt < 4; ++jt) {
        float p[4];
#pragma unroll
        for (int r = 0; r < 4; ++r) p[r] = __builtin_amdgcn_exp2f(s[jt][r]);
        pa[jt] = pack_bf16x4(p[0], p[1], p[2], p[3]);
      }
    }
    __builtin_amdgcn_s_setprio(1);
#pragma unroll
    for (int kb = 0; kb < 4; ++kb)
      lacc = MFMA16K16(ones4, pa[kb], lacc);
    // O += P * V : V b64 reads.
#pragma unroll
    for (int kb = 0; kb < 4; ++kb)
#pragma unroll
      for (int jd = 0; jd < 4; ++jd) {
        const short4v bv = *(const short4v*)(Vb + jd * 1024 + vbase[kb]);
        o[jd] = MFMA16K16(pa[kb], bv, o[jd]);
      }
    __builtin_amdgcn_s_setprio(0);
    buf += 1; if (buf >= 3) buf -= 3;
  }

  // lacc: D[m][q] all-rows-equal = lsum[q = lane&15]; redistribute to rows
  const int b = bh >> 4, h = bh & 15;
  float inv[4];
#pragma unroll
  for (int r = 0; r < 4; ++r)
    inv[r] = __builtin_amdgcn_rcpf(__shfl(lacc[0], quad * 4 + r));
#pragma unroll
  for (int jd = 0; jd < 4; ++jd)
#pragma unroll
    for (int r = 0; r < 4; ++r) {
      const int t = qrow0 + wave * 16 + quad * 4 + r;
      yb[((size_t)b * 2048 + t) * 1024 + h * 64 + jd * 16 + lr] =
          f2bf(o[jd][r] * inv[r]);
    }
}

extern "C" void kernel_launch(void* const* d_in, const int* in_sizes, int n_in,
                              void* d_out, int out_size, void* d_ws, size_t ws_size,
                              hipStream_t stream) {
  const float* x     = (const float*)d_in[0];   // (2,2048,1024)
  const float* Wqkv  = (const float*)d_in[1];   // (1024,3072)
  const float* bqkv  = (const float*)d_in[2];   // (3072,)
  const float* Wproj = (const float*)d_in[3];   // (1024,1024)
  const float* bproj = (const float*)d_in[4];   // (1024,)
  float* out = (float*)d_out;                   // (2,2048,1024) fp32

  char* ws = (char*)d_ws;
  unsigned short* xb     = (unsigned short*)(ws);              //  8.0 MB: x bf16 (4096x1024)
  unsigned short* wqkvT  = (unsigned short*)(ws + 8388608);    //  6.0 MB: Wqkv^T bf16 (3072x1024)
  unsigned short* wprojT = (unsigned short*)(ws + 14680064);   //  2.0 MB: Wproj^T bf16 (1024x1024)
  unsigned short* qbuf   = (unsigned short*)(ws + 16777216);   //  8.0 MB: Q (B,H,T,D), pre-scaled
  unsigned short* kbuf   = (unsigned short*)(ws + 25165824);   //  8.0 MB: K (B,H,T,D)
  unsigned short* vTbuf  = (unsigned short*)(ws + 33554432);   //  8.0 MB: V^T (B,H,D,T)
  unsigned short* ybuf   = (unsigned short*)(ws + 41943040);   //  8.0 MB: y (B,T,C) bf16

  prep<<<5120, 256, 0, stream>>>(x, xb, Wqkv, wqkvT, Wproj, wprojT);
  gemm_bt<0, 128><<<dim3(24, 32), 256, 0, stream>>>(xb, wqkvT, bqkv, nullptr,
                                                    qbuf, kbuf, vTbuf, 3072, 1024);
  attn<<<dim3(32, 32), 256, 0, stream>>>(qbuf, kbuf, vTbuf, ybuf);
  gemm_bt<1, 64><<<dim3(8, 64), 256, 0, stream>>>(ybuf, wprojT, bproj, out,
                                                  nullptr, nullptr, nullptr, 1024, 1024);
}

// Round 8
// 181.370 us; speedup vs baseline: 1.1853x; 1.0266x over previous
//
#include <hip/hip_runtime.h>

// CausalSelfAttention on MI355X (gfx950), bf16 MFMA pipeline.
// B=2 T=2048 C=1024 NH=16 HD=64.  M=B*T=4096.
//
// R19: consolidation.  R16/R17/R18 all tried to cash the q/k epilogue swap
// and all three lost 12-40 us in the K-loop codegen (runtime branch -> VGPR
// 132; dispatch split -> 1-2 blocks/CU; two-path inline -> duplicated AGPR
// accumulators, occupancy 14%).  The epilogue win is <=3-5 us (writes are
// posted, kernel at 14% HBM) — not worth the codegen risk.  Verdict:
//   QKV  = R4-exact core (MFMA(a,b), ONE accumulator, epilogue branch only
//          after the K-loop; scalar q/k stores accepted).  Proven 47.6 us.
//   proj = R7's swapped core + float4 full-line epilogue (separate
//          instantiation, proven non-regressing).
//   prep = merged single dispatch.  attn = R6-measured 43.5 us w/ setprio.
// attn bank-conflict note: 4.3M conflicts / ~1.6M LDS reads ~= 2.7/read =
// benign 2-way aliasing (free per m136) — not a lever; leave layout alone.

typedef __attribute__((ext_vector_type(8))) short short8;   // 8 x bf16 (4 VGPR)
typedef __attribute__((ext_vector_type(4))) short short4v;  // 4 x bf16 (2 VGPR, align 8)
typedef __attribute__((ext_vector_type(4))) float f32x4;    // MFMA 16x16 acc
typedef __attribute__((ext_vector_type(2))) unsigned int u32x2;

#define MFMA16(a, b, c) __builtin_amdgcn_mfma_f32_16x16x32_bf16((a), (b), (c), 0, 0, 0)
#define MFMA16K16(a, b, c) __builtin_amdgcn_mfma_f32_16x16x16bf16_1k((a), (b), (c), 0, 0, 0)

__device__ __forceinline__ unsigned short f2bf(float f) {
  unsigned u = __builtin_bit_cast(unsigned, f);
  u += 0x7fffu + ((u >> 16) & 1u);   // RNE
  return (unsigned short)(u >> 16);
}

__device__ __forceinline__ unsigned short f2bf_fast(float f) {
  // round-half-up: cheaper (2 VALU); |err| <= 2^-9 rel, fine for P/y
  return (unsigned short)((__builtin_bit_cast(unsigned, f) + 0x8000u) >> 16);
}

#if __has_builtin(__builtin_amdgcn_cvt_pk_bf16_f32)
typedef __attribute__((ext_vector_type(2))) __bf16 bf16x2;
__device__ __forceinline__ short4v pack_bf16x4(float a, float b, float c, float d) {
  bf16x2 lo = __builtin_amdgcn_cvt_pk_bf16_f32(a, b);
  bf16x2 hi = __builtin_amdgcn_cvt_pk_bf16_f32(c, d);
  u32x2 t;
  t[0] = __builtin_bit_cast(unsigned, lo);
  t[1] = __builtin_bit_cast(unsigned, hi);
  return __builtin_bit_cast(short4v, t);
}
#else
__device__ __forceinline__ short4v pack_bf16x4(float a, float b, float c, float d) {
  short4v r;
  r[0] = (short)f2bf_fast(a); r[1] = (short)f2bf_fast(b);
  r[2] = (short)f2bf_fast(c); r[3] = (short)f2bf_fast(d);
  return r;
}
#endif

__device__ __forceinline__ short4v pack_rne4(float a, float b, float c, float d) {
  short4v r;
  r[0] = (short)f2bf(a); r[1] = (short)f2bf(b);
  r[2] = (short)f2bf(c); r[3] = (short)f2bf(d);
  return r;
}

__device__ __forceinline__ void gl2lds16(const void* g, void* l) {
  // async global->LDS, 16B/lane; LDS dest = wave-uniform base + lane*16
  __builtin_amdgcn_global_load_lds(
      (__attribute__((address_space(1))) void*)g,
      (__attribute__((address_space(3))) void*)l,
      16, 0, 0);
}

// ---------------- merged prep: x->bf16 + both weight transposes ----------------
// blocks [0,4096): conv x (4096x1024 fp32 -> bf16)
// blocks [4096,4864): Wqkv (1024x3072) -> Wqkv^T bf16 (3072x1024), 48x16 tiles
// blocks [4864,5120): Wproj (1024x1024) -> Wproj^T bf16, 16x16 tiles
// Branch is block-uniform, so the __syncthreads in the transpose path is safe.
__global__ __launch_bounds__(256)
void prep(const float* __restrict__ x, unsigned short* __restrict__ xb,
          const float* __restrict__ Wqkv, unsigned short* __restrict__ wqkvT,
          const float* __restrict__ Wproj, unsigned short* __restrict__ wprojT) {
  __shared__ float tile[64][65];
  const int bx = blockIdx.x, tid = threadIdx.x;
  if (bx < 4096) {
    const int i = (bx * 256 + tid) * 4;
    float4 f = *(const float4*)(x + i);
    unsigned long long r = (unsigned long long)f2bf(f.x)
        | ((unsigned long long)f2bf(f.y) << 16)
        | ((unsigned long long)f2bf(f.z) << 32)
        | ((unsigned long long)f2bf(f.w) << 48);
    *(unsigned long long*)(xb + i) = r;
    return;
  }
  const float* W;
  unsigned short* WT;
  int n0, k0, N;
  if (bx < 4864) {
    const int idx = bx - 4096;            // 48 x 16 tiles, N=3072
    W = Wqkv; WT = wqkvT; N = 3072;
    n0 = (idx % 48) * 64; k0 = (idx / 48) * 64;
  } else {
    const int idx = bx - 4864;            // 16 x 16 tiles, N=1024
    W = Wproj; WT = wprojT; N = 1024;
    n0 = (idx % 16) * 64; k0 = (idx / 16) * 64;
  }
  const int K = 1024;
  const int c = tid & 63, rbase = tid >> 6;  // 4 rows per pass, 16 passes
#pragma unroll
  for (int i = 0; i < 16; ++i) {
    int r = i * 4 + rbase;
    tile[r][c] = W[(size_t)(k0 + r) * N + n0 + c];
  }
  __syncthreads();
#pragma unroll
  for (int i = 0; i < 16; ++i) {
    int r = i * 4 + rbase;
    WT[(size_t)(n0 + r) * K + k0 + c] = f2bf(tile[c][r]);
  }
}

// ---------------- GEMM core: staging + MFMA loop (templated operand order) ----
// R1 structure: single-buffered 32 KB LDS -> ~3 blocks/CU; stage -> sync ->
// compute -> sync; cross-block TLP hides the drain.
template <int SWAP, int MT>
__device__ __forceinline__ void gemm_core(
    const unsigned short* __restrict__ gA,
    const unsigned short* __restrict__ gB,
    unsigned short* As, unsigned short* Bs,
    int Kdim, int wave, int quad, int lr, int wm, int wn,
    f32x4 (&acc)[MT / 32][4]) {
  constexpr int IF = MT / 32;
  constexpr int RA = MT / 32;
  const size_t rstep = (size_t)32 * Kdim;
  for (int k0 = 0; k0 < Kdim; k0 += 64) {
#pragma unroll
    for (int rd = 0; rd < RA; ++rd)
      gl2lds16(gA + k0 + rd * rstep, As + rd * 2048 + wave * 512);
#pragma unroll
    for (int rd = 0; rd < 4; ++rd)
      gl2lds16(gB + k0 + rd * rstep, Bs + rd * 2048 + wave * 512);
    __syncthreads();
#pragma unroll
    for (int s = 0; s < 2; ++s) {
      const int sw = ((s * 4 + quad) ^ (lr & 7)) * 8;
      short8 a[IF], b[4];
#pragma unroll
      for (int i = 0; i < IF; ++i)
        a[i] = *(const short8*)(As + (wm * (MT / 2) + i * 16 + lr) * 64 + sw);
#pragma unroll
      for (int j = 0; j < 4; ++j)
        b[j] = *(const short8*)(Bs + (wn * 64 + j * 16 + lr) * 64 + sw);
#pragma unroll
      for (int i = 0; i < IF; ++i)
#pragma unroll
        for (int j = 0; j < 4; ++j) {
          if constexpr (SWAP)
            acc[i][j] = MFMA16(b[j], a[i], acc[i][j]);
          else
            acc[i][j] = MFMA16(a[i], b[j], acc[i][j]);
        }
    }
    __syncthreads();
  }
}

// ---------------- GEMM kernel: C = A(MxK) * BT(NxK)^T ----------------
// EPI==0: QKV, one dispatch (24,32).  R4-exact: ONE core (MFMA(a,b)), ONE
//   accumulator, epilogue branch after the K-loop.
//   C/D layout: col = lane&15 (n), row = quad*4 + reg (m).
//   q/k: scalar 2-B stores (write-amp accepted — not on critical path).
//   v:   4 m-consecutive packed -> short4v into V^T (B,H,D,T).
// EPI==1: proj, swapped core (MFMA(b,a)) -> 4 n-consecutive per thread ->
//   float4 full-line stores + bias.
template <int EPI, int MT>
__global__ __launch_bounds__(256)
void gemm_bt(const unsigned short* __restrict__ A,
             const unsigned short* __restrict__ BT,
             const float* __restrict__ bias,
             float* __restrict__ outF,
             unsigned short* __restrict__ q_out,
             unsigned short* __restrict__ k_out,
             unsigned short* __restrict__ vT_out,
             int Ndim, int Kdim) {
  constexpr int IF = MT / 32;
  __shared__ __align__(16) unsigned short As[MT * 64];
  __shared__ __align__(16) unsigned short Bs[128 * 64];
  const int tid = threadIdx.x;
  const int wave = tid >> 6, lane = tid & 63;
  const int quad = lane >> 4, lr = lane & 15;
  const int wm = wave >> 1, wn = wave & 1;
  const int m0 = blockIdx.y * MT, n0 = blockIdx.x * 128;

  const int r_l = tid >> 3;
  const int cg = (tid & 7) ^ (r_l & 7);
  const unsigned short* gA = A + (size_t)(m0 + r_l) * Kdim + cg * 8;
  const unsigned short* gB = BT + (size_t)(n0 + r_l) * Kdim + cg * 8;

  if constexpr (EPI == 1) {
    f32x4 acc[IF][4] = {};
    gemm_core<1, MT>(gA, gB, As, Bs, Kdim, wave, quad, lr, wm, wn, acc);
    // proj (swapped): float4 store, full-line coalesced across quads
#pragma unroll
    for (int j = 0; j < 4; ++j) {
      const int nb = n0 + wn * 64 + j * 16 + quad * 4;
      const float4 bi = *(const float4*)(bias + nb);
#pragma unroll
      for (int i = 0; i < IF; ++i) {
        const int m = m0 + wm * (MT / 2) + i * 16 + lr;
        float4 o4;
        o4.x = acc[i][j][0] + bi.x;
        o4.y = acc[i][j][1] + bi.y;
        o4.z = acc[i][j][2] + bi.z;
        o4.w = acc[i][j][3] + bi.w;
        *(float4*)(outF + (size_t)m * Ndim + nb) = o4;
      }
    }
  } else {
    // ---- QKV: R4-exact single core + post-loop epilogue branch ----
    f32x4 acc[IF][4] = {};
    gemm_core<0, MT>(gA, gB, As, Bs, Kdim, wave, quad, lr, wm, wn, acc);
    const int row_t = wm * (MT / 2) + quad * 4;
    const int col_t = wn * 64 + lr;
    const int sec = n0 >> 10;                 // block-uniform: 0=q 1=k 2=v
    const float scl = (sec == 0) ? 0.18033688f : 1.0f;  // 0.125*log2(e) into Q
#pragma unroll
    for (int j = 0; j < 4; ++j) {
      const int n = n0 + col_t + j * 16;
      const float bi = bias[n];
      const int nn = n & 1023, h = nn >> 6, d = nn & 63;
#pragma unroll
      for (int i = 0; i < IF; ++i) {
        const int m_base = m0 + row_t + i * 16;   // 4 consecutive m for r=0..3
        const int bb = m_base >> 11, t0 = m_base & 2047;
        const int bh = bb * 16 + h;
        if (sec == 2) {
          short4v pk = pack_rne4(acc[i][j][0] + bi, acc[i][j][1] + bi,
                                 acc[i][j][2] + bi, acc[i][j][3] + bi);
          *(short4v*)(vT_out + ((size_t)bh * 64 + d) * 2048 + t0) = pk;
        } else {
          unsigned short* dst = (sec == 0 ? q_out : k_out) + (size_t)bh * 131072 + t0 * 64 + d;
#pragma unroll
          for (int r = 0; r < 4; ++r)
            dst[r * 64] = f2bf((acc[i][j][r] + bi) * scl);
        }
      }
    }
  }
}

// ---------------- flash-style causal attention, 64-row q-tiles ----------------
// m=0 softmax; Q PRE-SCALED by 0.125*log2(e) so P = exp2(S).
// Transposed-S trick: S^T = K*Q^T; its C-layout IS the K=16 A-operand layout.
// Block = 4 waves x 16 q-rows = 64 q-rows; K/V fragment LDS reads shared.
// 1024 blocks, heavy-first (LPT) dispatch, bh%8 pins XCD for K/V L2 locality.
// Triple-buffered K/V staged TWO tiles ahead; raw s_barrier + manual
// s_waitcnt vmcnt(4) so the newest stage stays in flight across the barrier.
// T5 s_setprio(1) around MFMA clusters (independent blocks -> +4-7% regime).
// q,k: (B,H,T,D); v: (B,H,D,T); y: (B,T,C).
__global__ __launch_bounds__(256, 3)
void attn(const unsigned short* __restrict__ qbuf,
          const unsigned short* __restrict__ kbuf,
          const unsigned short* __restrict__ vT,
          unsigned short* __restrict__ yb) {
  __shared__ __align__(16) unsigned short Ks[3][4096];
  __shared__ __align__(16) unsigned short Vs[3][4096];
  const int tid = threadIdx.x, wave = tid >> 6, lane = tid & 63;
  const int quad = lane >> 4, lr = lane & 15;
  const int bh = blockIdx.x;                  // heads fastest: bh%8 pins XCD
  const int qt = 31 - (int)blockIdx.y;        // heavy-first for refill (LPT)
  const int qrow0 = qt * 64;                  // tile base (head-local)

  const unsigned short* qp0 = qbuf + (size_t)bh * 131072;
  const unsigned short* kp0 = kbuf + (size_t)bh * 131072;
  const unsigned short* vp0 = vT   + (size_t)bh * 131072;

  // Q fragments (B-operand of S^T: n = q = lane&15, k = d = quad*8+j)
  short8 aq[2];
  {
    const unsigned short* qp =
        qp0 + (size_t)(qrow0 + wave * 16 + lr) * 64 + quad * 8;
    aq[0] = *(const short8*)qp;
    aq[1] = *(const short8*)(qp + 32);
  }

  short4v ones4;
#pragma unroll
  for (int i = 0; i < 4; ++i) ones4[i] = (short)0x3F80;  // bf16 1.0

  // DMA staging: thread t -> (row=t>>3 in 0..31 (+32), cg=(t&7)^(row&7))
  const int sr = tid >> 3;
  const int scg = (tid & 7) ^ (sr & 7);
  // K fragment bases (A-operand: m = key = lr (+jt*16), k = d = (quad+4h)*8), swizzled
  int kbase[2];
#pragma unroll
  for (int h = 0; h < 2; ++h)
    kbase[h] = lr * 64 + (((quad + 4 * h) ^ (lr & 7)) << 3);
  // V b64 bases per key-block kb: element (row = d = lr (+jd*16), col = kb*16+quad*4)
  int vbase[4];
#pragma unroll
  for (int kb = 0; kb < 4; ++kb)
    vbase[kb] = lr * 64 + (((2 * kb + (quad >> 1)) ^ (lr & 7)) << 3) + (quad & 1) * 4;

  f32x4 o[4] = {};
  f32x4 lacc = {};

  auto stage = [&](int buf, int kt) {
    const unsigned short* kg = kp0 + (size_t)(kt * 64 + sr) * 64 + scg * 8;
    const unsigned short* vg = vp0 + (size_t)sr * 2048 + kt * 64 + scg * 8;
    gl2lds16(kg,             &Ks[buf][wave * 512]);
    gl2lds16(kg + 32 * 64,   &Ks[buf][2048 + wave * 512]);
    gl2lds16(vg,             &Vs[buf][wave * 512]);
    gl2lds16(vg + 32 * 2048, &Vs[buf][2048 + wave * 512]);
  };

  const int dlast = qt;           // diagonal k-tile index == last tile
  stage(0, 0);
  if (dlast >= 1) stage(1, 1);
  int buf = 0;
  for (int kt = 0; kt <= dlast; ++kt) {
    // Drain own DMAs for tile kt (issued 2 iters ago) but keep the newest
    // stage (4 instrs, tile kt+1) in flight. Each wave drains its own; the
    // barrier then guarantees all waves' contributions to tile kt are in LDS.
    if (kt < dlast) __builtin_amdgcn_s_waitcnt(0x0F74);  // vmcnt(4)
    else            __builtin_amdgcn_s_waitcnt(0x0F70);  // vmcnt(0)
    __builtin_amdgcn_s_barrier();
    if (kt + 2 <= dlast) {
      int nb = buf + 2; if (nb >= 3) nb -= 3;
      stage(nb, kt + 2);          // overwrites buffer of tile kt-1 (consumed)
    }
    const unsigned short* Kb = Ks[buf];
    const unsigned short* Vb = Vs[buf];
    short8 bk[4][2];
#pragma unroll
    for (int jt = 0; jt < 4; ++jt) {
      bk[jt][0] = *(const short8*)(Kb + jt * 1024 + kbase[0]);
      bk[jt][1] = *(const short8*)(Kb + jt * 1024 + kbase[1]);
    }
    // S^T, exp2 (+causal mask on the diagonal tile), pack; lsum.
    f32x4 s[4] = {};
    __builtin_amdgcn_s_setprio(1);
#pragma unroll
    for (int jt = 0; jt < 4; ++jt) {
      s[jt] = MFMA16(bk[jt][0], aq[0], s[jt]);
      s[jt] = MFMA16(bk[jt][1], aq[1], s[jt]);
    }
    __builtin_amdgcn_s_setprio(0);
    short4v pa[4];
    if (kt == dlast) {            // diagonal: key-local > wave*16+lr masked
      const int qloc = wave * 16 + lr;
#pragma unroll
      for (int jt = 0; jt < 4; ++jt) {
        float p[4];
#pragma unroll
        for (int r = 0; r < 4; ++r) {
          p[r] = __builtin_amdgcn_exp2f(s[jt][r]);
          if (jt * 16 + quad * 4 + r > qloc) p[r] = 0.f;
        }
        pa[jt] = pack_bf16x4(p[0], p[1], p[2], p[3]);
      }
    } else {
#pragma unroll
      for (int jt = 0; jt < 4; ++jt) {
        float p[4];
#pragma unroll
        for (int r = 0; r < 4; ++r) p[r] = __builtin_amdgcn_exp2f(s[jt][r]);
        pa[jt] = pack_bf16x4(p[0], p[1], p[2], p[3]);
      }
    }
    __builtin_amdgcn_s_setprio(1);
#pragma unroll
    for (int kb = 0; kb < 4; ++kb)
      lacc = MFMA16K16(ones4, pa[kb], lacc);
    // O += P * V : V b64 reads.
#pragma unroll
    for (int kb = 0; kb < 4; ++kb)
#pragma unroll
      for (int jd = 0; jd < 4; ++jd) {
        const short4v bv = *(const short4v*)(Vb + jd * 1024 + vbase[kb]);
        o[jd] = MFMA16K16(pa[kb], bv, o[jd]);
      }
    __builtin_amdgcn_s_setprio(0);
    buf += 1; if (buf >= 3) buf -= 3;
  }

  // lacc: D[m][q] all-rows-equal = lsum[q = lane&15]; redistribute to rows
  const int b = bh >> 4, h = bh & 15;
  float inv[4];
#pragma unroll
  for (int r = 0; r < 4; ++r)
    inv[r] = __builtin_amdgcn_rcpf(__shfl(lacc[0], quad * 4 + r));
#pragma unroll
  for (int jd = 0; jd < 4; ++jd)
#pragma unroll
    for (int r = 0; r < 4; ++r) {
      const int t = qrow0 + wave * 16 + quad * 4 + r;
      yb[((size_t)b * 2048 + t) * 1024 + h * 64 + jd * 16 + lr] =
          f2bf(o[jd][r] * inv[r]);
    }
}

extern "C" void kernel_launch(void* const* d_in, const int* in_sizes, int n_in,
                              void* d_out, int out_size, void* d_ws, size_t ws_size,
                              hipStream_t stream) {
  const float* x     = (const float*)d_in[0];   // (2,2048,1024)
  const float* Wqkv  = (const float*)d_in[1];   // (1024,3072)
  const float* bqkv  = (const float*)d_in[2];   // (3072,)
  const float* Wproj = (const float*)d_in[3];   // (1024,1024)
  const float* bproj = (const float*)d_in[4];   // (1024,)
  float* out = (float*)d_out;                   // (2,2048,1024) fp32

  char* ws = (char*)d_ws;
  unsigned short* xb     = (unsigned short*)(ws);              //  8.0 MB: x bf16 (4096x1024)
  unsigned short* wqkvT  = (unsigned short*)(ws + 8388608);    //  6.0 MB: Wqkv^T bf16 (3072x1024)
  unsigned short* wprojT = (unsigned short*)(ws + 14680064);   //  2.0 MB: Wproj^T bf16 (1024x1024)
  unsigned short* qbuf   = (unsigned short*)(ws + 16777216);   //  8.0 MB: Q (B,H,T,D), pre-scaled
  unsigned short* kbuf   = (unsigned short*)(ws + 25165824);   //  8.0 MB: K (B,H,T,D)
  unsigned short* vTbuf  = (unsigned short*)(ws + 33554432);   //  8.0 MB: V^T (B,H,D,T)
  unsigned short* ybuf   = (unsigned short*)(ws + 41943040);   //  8.0 MB: y (B,T,C) bf16

  prep<<<5120, 256, 0, stream>>>(x, xb, Wqkv, wqkvT, Wproj, wprojT);
  gemm_bt<0, 128><<<dim3(24, 32), 256, 0, stream>>>(xb, wqkvT, bqkv, nullptr,
                                                    qbuf, kbuf, vTbuf, 3072, 1024);
  attn<<<dim3(32, 32), 256, 0, stream>>>(qbuf, kbuf, vTbuf, ybuf);
  gemm_bt<1, 64><<<dim3(8, 64), 256, 0, stream>>>(ybuf, wprojT, bproj, out,
                                                  nullptr, nullptr, nullptr, 1024, 1024);
}